// Round 1
// baseline (408.735 us; speedup 1.0000x reference)
//
#include <hip/hip_runtime.h>

typedef __attribute__((ext_vector_type(8))) short short8;
typedef __attribute__((ext_vector_type(4))) float f32x4;
typedef __attribute__((ext_vector_type(4))) unsigned short ush4;

static __device__ __forceinline__ unsigned short f2bf(float f) {
  unsigned int u = __builtin_bit_cast(unsigned int, f);
  u = u + 0x7fffu + ((u >> 16) & 1u);
  return (unsigned short)(u >> 16);
}

// Static problem config
// B=1, Z=H=W=64, C=96, NH=3, HD=32, WS=4, SS=2, N=64 tok/window, NW=4096
constexpr float SCL = 0.17677669529663687f;  // 32^-0.5
constexpr int XPAD = 104;   // 208 B rows (mult of 16B, not mult of 128B)
constexpr int QKPAD = 200;  // 400 B rows
constexpr int VTPAD = 72;   // 144 B rows
constexpr int PPAD = 72;
constexpr int H1PAD = 392;  // 784 B rows

// ---------------- prep: convert weights to bf16 in workspace ----------------
__global__ void prep_weights(const float* __restrict__ qkvw, const float* __restrict__ projw,
                             const float* __restrict__ fc1w, const float* __restrict__ fc2w,
                             unsigned short* __restrict__ ws) {
  int i = blockIdx.x * 256 + threadIdx.x;
  if (i < 27648) ws[i] = f2bf(qkvw[i]);
  if (i < 9216)  ws[27648 + i] = f2bf(projw[i]);
  if (i < 36864) { ws[36864 + i] = f2bf(fc1w[i]); ws[73728 + i] = f2bf(fc2w[i]); }
}

// ---------------- fused LN1 + shift + window attention + proj + residual ----
__global__ __launch_bounds__(256, 2) void attn_kernel(
    const float* __restrict__ x, const float* __restrict__ n1w, const float* __restrict__ n1b,
    const float* __restrict__ qkvb, const float* __restrict__ relbias,
    const float* __restrict__ projb, const unsigned short* __restrict__ wq,
    const unsigned short* __restrict__ wp, float* __restrict__ out) {
  __shared__ unsigned short Xo[64 * XPAD];   // X_ln, later O (heads concat)
  __shared__ unsigned short QK[64 * QKPAD];  // cols 0..95 Q, 96..191 K
  __shared__ unsigned short Vt[96 * VTPAD];  // [h*32+d][token]
  __shared__ unsigned short Pb[64 * PPAD];   // P (softmax probs) bf16
  __shared__ float relb[1029];               // (343,3) rel bias table

  const int tid = threadIdx.x;
  const int bid = blockIdx.x;
  const int wz = bid >> 8, wh = (bid >> 4) & 15, ww = bid & 15;
  const int wave = tid >> 6, lane = tid & 63;
  const int ln = lane & 15, kg = lane >> 4;

  for (int i = tid; i < 1029; i += 256) relb[i] = relbias[i];

  // Phase 0: gather (cyclic shift) + LayerNorm1 -> Xo (bf16)
  {
    const int n = tid >> 2, part = tid & 3;
    const int lz = n >> 4, lh = (n >> 2) & 3, lw = n & 3;
    const int sz = (wz * 4 + lz + 2) & 63;
    const int sh = (wh * 4 + lh + 2) & 63;
    const int sw = (ww * 4 + lw + 2) & 63;
    const float* px = x + (size_t)((sz * 64 + sh) * 64 + sw) * 96 + part * 24;
    float4 v[6];
#pragma unroll
    for (int j = 0; j < 6; ++j) v[j] = ((const float4*)px)[j];
    float s = 0.f, sq = 0.f;
#pragma unroll
    for (int j = 0; j < 6; ++j) {
      s += v[j].x + v[j].y + v[j].z + v[j].w;
      sq += v[j].x * v[j].x + v[j].y * v[j].y + v[j].z * v[j].z + v[j].w * v[j].w;
    }
    s += __shfl_xor(s, 1);  s += __shfl_xor(s, 2);
    sq += __shfl_xor(sq, 1); sq += __shfl_xor(sq, 2);
    const float mean = s * (1.f / 96.f);
    const float var = sq * (1.f / 96.f) - mean * mean;
    const float rs = rsqrtf(var + 1e-5f);
    const float4* g4 = (const float4*)(n1w + part * 24);
    const float4* b4 = (const float4*)(n1b + part * 24);
#pragma unroll
    for (int j = 0; j < 6; ++j) {
      float4 g = g4[j], b = b4[j];
      ush4 o;
      o.x = f2bf((v[j].x - mean) * rs * g.x + b.x);
      o.y = f2bf((v[j].y - mean) * rs * g.y + b.y);
      o.z = f2bf((v[j].z - mean) * rs * g.z + b.z);
      o.w = f2bf((v[j].w - mean) * rs * g.w + b.w);
      *(ush4*)&Xo[n * XPAD + part * 24 + j * 4] = o;
    }
  }
  __syncthreads();

  // Phase 1: QKV GEMM. wave owns row-tile mt=wave; loops 18 col-tiles.
  {
    short8 a[3];
#pragma unroll
    for (int ks = 0; ks < 3; ++ks)
      a[ks] = *(const short8*)&Xo[(wave * 16 + ln) * XPAD + ks * 32 + kg * 8];
    for (int nt = 0; nt < 18; ++nt) {
      const int oc = nt * 16 + ln;
      f32x4 acc = {0.f, 0.f, 0.f, 0.f};
#pragma unroll
      for (int ks = 0; ks < 3; ++ks) {
        short8 b = *(const short8*)&wq[(size_t)oc * 96 + ks * 32 + kg * 8];
        acc = __builtin_amdgcn_mfma_f32_16x16x32_bf16(a[ks], b, acc, 0, 0, 0);
      }
      const float bias = qkvb[oc];
      if (nt < 12) {
#pragma unroll
        for (int r = 0; r < 4; ++r)
          QK[(wave * 16 + kg * 4 + r) * QKPAD + oc] = f2bf(acc[r] + bias);
      } else {
        const int vc = oc - 192, hh = vc >> 5, d = vc & 31;
        ush4 o;
        o.x = f2bf(acc[0] + bias); o.y = f2bf(acc[1] + bias);
        o.z = f2bf(acc[2] + bias); o.w = f2bf(acc[3] + bias);
        *(ush4*)&Vt[(hh * 32 + d) * VTPAD + wave * 16 + kg * 4] = o;
      }
    }
  }
  __syncthreads();

  // Phase 2: per-head QK^T -> softmax (in-register) -> PV -> O (in Xo)
  const bool bz = (wz == 15), bhm = (wh == 15), bwm = (ww == 15);
  const int rowbase = wave * 16 + kg * 4;
  for (int h = 0; h < 3; ++h) {
    short8 qa = *(const short8*)&QK[(wave * 16 + ln) * QKPAD + h * 32 + kg * 8];
    f32x4 sacc[4];
#pragma unroll
    for (int nt = 0; nt < 4; ++nt) {
      short8 kb = *(const short8*)&QK[(nt * 16 + ln) * QKPAD + 96 + h * 32 + kg * 8];
      f32x4 z = {0.f, 0.f, 0.f, 0.f};
      sacc[nt] = __builtin_amdgcn_mfma_f32_16x16x32_bf16(qa, kb, z, 0, 0, 0);
    }
#pragma unroll
    for (int r = 0; r < 4; ++r) {
      const int row = rowbase + r;
      const int iz = row >> 4, ih = (row >> 2) & 3, iw = row & 3;
      const int ci = (bz ? (iz < 2 ? 9 : 18) : 0) + (bhm ? (ih < 2 ? 3 : 6) : 0) +
                     (bwm ? (iw < 2 ? 1 : 2) : 0);
      float t[4];
      float mx = -1e30f;
#pragma unroll
      for (int nt = 0; nt < 4; ++nt) {
        const int col = nt * 16 + ln;
        const int jz = col >> 4, jh = (col >> 2) & 3, jw = col & 3;
        const int cj = (bz ? (jz < 2 ? 9 : 18) : 0) + (bhm ? (jh < 2 ? 3 : 6) : 0) +
                       (bwm ? (jw < 2 ? 1 : 2) : 0);
        const int idx = (iz - jz + 3) * 49 + (ih - jh + 3) * 7 + (iw - jw + 3);
        float tv = sacc[nt][r] * SCL + relb[idx * 3 + h];
        if (ci != cj) tv -= 100.f;
        t[nt] = tv;
        mx = fmaxf(mx, tv);
      }
      mx = fmaxf(mx, __shfl_xor(mx, 1));
      mx = fmaxf(mx, __shfl_xor(mx, 2));
      mx = fmaxf(mx, __shfl_xor(mx, 4));
      mx = fmaxf(mx, __shfl_xor(mx, 8));
      float sum = 0.f;
#pragma unroll
      for (int nt = 0; nt < 4; ++nt) { t[nt] = __expf(t[nt] - mx); sum += t[nt]; }
      sum += __shfl_xor(sum, 1);
      sum += __shfl_xor(sum, 2);
      sum += __shfl_xor(sum, 4);
      sum += __shfl_xor(sum, 8);
      const float inv = 1.f / sum;
#pragma unroll
      for (int nt = 0; nt < 4; ++nt)
        Pb[row * PPAD + nt * 16 + ln] = f2bf(t[nt] * inv);
    }
    __syncthreads();  // P visible (safety; each wave only reads its own rows)
    // PV: O[rows of this wave][h*32 + 0..31]
#pragma unroll
    for (int dt = 0; dt < 2; ++dt) {
      f32x4 oacc = {0.f, 0.f, 0.f, 0.f};
#pragma unroll
      for (int ks = 0; ks < 2; ++ks) {
        short8 pa = *(const short8*)&Pb[(wave * 16 + ln) * PPAD + ks * 32 + kg * 8];
        short8 vb = *(const short8*)&Vt[(h * 32 + dt * 16 + ln) * VTPAD + ks * 32 + kg * 8];
        oacc = __builtin_amdgcn_mfma_f32_16x16x32_bf16(pa, vb, oacc, 0, 0, 0);
      }
#pragma unroll
      for (int r = 0; r < 4; ++r)
        Xo[(rowbase + r) * XPAD + h * 32 + dt * 16 + ln] = f2bf(oacc[r]);
    }
    __syncthreads();  // before next head overwrites Pb (safety)
  }
  __syncthreads();

  // Phase 3: proj + shortcut, scatter back (reverse shift) to d_out (= x2)
  {
    short8 a[3];
#pragma unroll
    for (int ks = 0; ks < 3; ++ks)
      a[ks] = *(const short8*)&Xo[(wave * 16 + ln) * XPAD + ks * 32 + kg * 8];
    for (int nt = 0; nt < 6; ++nt) {
      f32x4 acc = {0.f, 0.f, 0.f, 0.f};
#pragma unroll
      for (int ks = 0; ks < 3; ++ks) {
        short8 b = *(const short8*)&wp[(size_t)(nt * 16 + ln) * 96 + ks * 32 + kg * 8];
        acc = __builtin_amdgcn_mfma_f32_16x16x32_bf16(a[ks], b, acc, 0, 0, 0);
      }
      const int col = nt * 16 + ln;
      const float pbv = projb[col];
#pragma unroll
      for (int r = 0; r < 4; ++r) {
        const int n = rowbase + r;
        const int lz = n >> 4, lh = (n >> 2) & 3, lw = n & 3;
        const int oz = (wz * 4 + lz + 2) & 63;
        const int oh = (wh * 4 + lh + 2) & 63;
        const int ow = (ww * 4 + lw + 2) & 63;
        const size_t tix = (size_t)((oz * 64 + oh) * 64 + ow) * 96 + col;
        out[tix] = x[tix] + acc[r] + pbv;
      }
    }
  }
}

// ---------------- fused LN2 + FC1 + GELU + FC2 + residual -------------------
__global__ __launch_bounds__(256, 2) void mlp_kernel(
    const float* __restrict__ n2w, const float* __restrict__ n2b,
    const unsigned short* __restrict__ w1, const float* __restrict__ b1,
    const unsigned short* __restrict__ w2, const float* __restrict__ b2,
    float* __restrict__ out) {
  __shared__ unsigned short Xl[64 * XPAD];
  __shared__ unsigned short H1[64 * H1PAD];
  const int tid = threadIdx.x;
  const size_t r0 = (size_t)blockIdx.x * 64;
  const int wave = tid >> 6, lane = tid & 63;
  const int ln = lane & 15, kg = lane >> 4;

  // LN2 on x2 (= current d_out)
  {
    const int n = tid >> 2, part = tid & 3;
    const float* px = out + (r0 + n) * 96 + part * 24;
    float4 v[6];
#pragma unroll
    for (int j = 0; j < 6; ++j) v[j] = ((const float4*)px)[j];
    float s = 0.f, sq = 0.f;
#pragma unroll
    for (int j = 0; j < 6; ++j) {
      s += v[j].x + v[j].y + v[j].z + v[j].w;
      sq += v[j].x * v[j].x + v[j].y * v[j].y + v[j].z * v[j].z + v[j].w * v[j].w;
    }
    s += __shfl_xor(s, 1);  s += __shfl_xor(s, 2);
    sq += __shfl_xor(sq, 1); sq += __shfl_xor(sq, 2);
    const float mean = s * (1.f / 96.f);
    const float var = sq * (1.f / 96.f) - mean * mean;
    const float rs = rsqrtf(var + 1e-5f);
    const float4* g4 = (const float4*)(n2w + part * 24);
    const float4* b4 = (const float4*)(n2b + part * 24);
#pragma unroll
    for (int j = 0; j < 6; ++j) {
      float4 g = g4[j], b = b4[j];
      ush4 o;
      o.x = f2bf((v[j].x - mean) * rs * g.x + b.x);
      o.y = f2bf((v[j].y - mean) * rs * g.y + b.y);
      o.z = f2bf((v[j].z - mean) * rs * g.z + b.z);
      o.w = f2bf((v[j].w - mean) * rs * g.w + b.w);
      *(ush4*)&Xl[n * XPAD + part * 24 + j * 4] = o;
    }
  }
  __syncthreads();

  // FC1 + GELU(exact erf) -> H1 (bf16, LDS only)
  {
    short8 a[3];
#pragma unroll
    for (int ks = 0; ks < 3; ++ks)
      a[ks] = *(const short8*)&Xl[(wave * 16 + ln) * XPAD + ks * 32 + kg * 8];
    for (int nt = 0; nt < 24; ++nt) {
      f32x4 acc = {0.f, 0.f, 0.f, 0.f};
#pragma unroll
      for (int ks = 0; ks < 3; ++ks) {
        short8 b = *(const short8*)&w1[(size_t)(nt * 16 + ln) * 96 + ks * 32 + kg * 8];
        acc = __builtin_amdgcn_mfma_f32_16x16x32_bf16(a[ks], b, acc, 0, 0, 0);
      }
      const int col = nt * 16 + ln;
      const float bb = b1[col];
#pragma unroll
      for (int r = 0; r < 4; ++r) {
        const float v = acc[r] + bb;
        const float gl = 0.5f * v * (1.f + erff(v * 0.70710678118654752f));
        H1[(wave * 16 + kg * 4 + r) * H1PAD + col] = f2bf(gl);
      }
    }
  }
  __syncthreads();

  // FC2 + residual (read-modify-write d_out)
  {
    short8 a[12];
#pragma unroll
    for (int ks = 0; ks < 12; ++ks)
      a[ks] = *(const short8*)&H1[(wave * 16 + ln) * H1PAD + ks * 32 + kg * 8];
    for (int nt = 0; nt < 6; ++nt) {
      f32x4 acc = {0.f, 0.f, 0.f, 0.f};
#pragma unroll
      for (int ks = 0; ks < 12; ++ks) {
        short8 b = *(const short8*)&w2[(size_t)(nt * 16 + ln) * 384 + ks * 32 + kg * 8];
        acc = __builtin_amdgcn_mfma_f32_16x16x32_bf16(a[ks], b, acc, 0, 0, 0);
      }
      const int col = nt * 16 + ln;
      const float bb = b2[col];
#pragma unroll
      for (int r = 0; r < 4; ++r) {
        const size_t row = r0 + wave * 16 + kg * 4 + r;
        out[row * 96 + col] = out[row * 96 + col] + acc[r] + bb;
      }
    }
  }
}

extern "C" void kernel_launch(void* const* d_in, const int* in_sizes, int n_in,
                              void* d_out, int out_size, void* d_ws, size_t ws_size,
                              hipStream_t stream) {
  const float* x    = (const float*)d_in[0];
  const float* n1w  = (const float*)d_in[1];
  const float* n1b  = (const float*)d_in[2];
  const float* qkvw = (const float*)d_in[3];
  const float* qkvb = (const float*)d_in[4];
  const float* relb = (const float*)d_in[5];
  const float* pw   = (const float*)d_in[6];
  const float* pb   = (const float*)d_in[7];
  const float* n2w  = (const float*)d_in[8];
  const float* n2b  = (const float*)d_in[9];
  const float* w1   = (const float*)d_in[10];
  const float* b1   = (const float*)d_in[11];
  const float* w2   = (const float*)d_in[12];
  const float* b2   = (const float*)d_in[13];
  float* out = (float*)d_out;

  unsigned short* wsq = (unsigned short*)d_ws;   // 27648 bf16
  unsigned short* wsp = wsq + 27648;             // 9216
  unsigned short* ws1 = wsp + 9216;              // 36864
  unsigned short* ws2 = ws1 + 36864;             // 36864

  hipLaunchKernelGGL(prep_weights, dim3(144), dim3(256), 0, stream, qkvw, pw, w1, w2, wsq);
  hipLaunchKernelGGL(attn_kernel, dim3(4096), dim3(256), 0, stream,
                     x, n1w, n1b, qkvb, relb, pb, wsq, wsp, out);
  hipLaunchKernelGGL(mlp_kernel, dim3(4096), dim3(256), 0, stream,
                     n2w, n2b, ws1, b1, ws2, b2, out);
}

// Round 2
// 248.977 us; speedup vs baseline: 1.6417x; 1.6417x over previous
//
#include <hip/hip_runtime.h>

typedef __attribute__((ext_vector_type(8))) short short8;
typedef __attribute__((ext_vector_type(4))) float f32x4;
typedef __attribute__((ext_vector_type(4))) unsigned short ush4;

static __device__ __forceinline__ unsigned short f2bf(float f) {
  unsigned int u = __builtin_bit_cast(unsigned int, f);
  u = u + 0x7fffu + ((u >> 16) & 1u);
  return (unsigned short)(u >> 16);
}

// Static problem config
// B=1, Z=H=W=64, C=96, NH=3, HD=32, WS=4, SS=2, N=64 tok/window, NW=4096
constexpr float SCL = 0.17677669529663687f;  // 32^-0.5
constexpr int XPAD = 104;   // 208 B rows (mult of 16B)
constexpr int QKPAD = 200;  // 400 B rows
constexpr int VTPAD = 72;   // 144 B rows
constexpr int PPAD = 72;
constexpr int MXP = 104;    // mlp row pitch (bf16 elems)

// ---------------- prep: convert weights to bf16 in workspace ----------------
__global__ void prep_weights(const float* __restrict__ qkvw, const float* __restrict__ projw,
                             const float* __restrict__ fc1w, const float* __restrict__ fc2w,
                             unsigned short* __restrict__ ws) {
  int i = blockIdx.x * 256 + threadIdx.x;
  if (i < 27648) ws[i] = f2bf(qkvw[i]);
  if (i < 9216)  ws[27648 + i] = f2bf(projw[i]);
  if (i < 36864) { ws[36864 + i] = f2bf(fc1w[i]); ws[73728 + i] = f2bf(fc2w[i]); }
}

// ---------------- fused LN1 + shift + window attention + proj + residual ----
__global__ __launch_bounds__(256, 2) void attn_kernel(
    const float* __restrict__ x, const float* __restrict__ n1w, const float* __restrict__ n1b,
    const float* __restrict__ qkvb, const float* __restrict__ relbias,
    const float* __restrict__ projb, const unsigned short* __restrict__ wq,
    const unsigned short* __restrict__ wp, float* __restrict__ out) {
  __shared__ unsigned short Xo[64 * XPAD];   // X_ln, later O (heads concat)
  __shared__ unsigned short QK[64 * QKPAD];  // cols 0..95 Q, 96..191 K
  __shared__ unsigned short Vt[96 * VTPAD];  // [h*32+d][token]
  __shared__ unsigned short Pb[64 * PPAD];   // P (softmax probs) bf16
  __shared__ float relb[1029];               // (343,3) rel bias table

  const int tid = threadIdx.x;
  const int bid = blockIdx.x;
  const int wz = bid >> 8, wh = (bid >> 4) & 15, ww = bid & 15;
  const int wave = tid >> 6, lane = tid & 63;
  const int ln = lane & 15, kg = lane >> 4;

  for (int i = tid; i < 1029; i += 256) relb[i] = relbias[i];

  // Phase 0: gather (cyclic shift) + LayerNorm1 -> Xo (bf16). Wave-local rows.
  {
    const int n = tid >> 2, part = tid & 3;
    const int lz = n >> 4, lh = (n >> 2) & 3, lw = n & 3;
    const int sz = (wz * 4 + lz + 2) & 63;
    const int sh = (wh * 4 + lh + 2) & 63;
    const int sw = (ww * 4 + lw + 2) & 63;
    const float* px = x + (size_t)((sz * 64 + sh) * 64 + sw) * 96 + part * 24;
    float4 v[6];
#pragma unroll
    for (int j = 0; j < 6; ++j) v[j] = ((const float4*)px)[j];
    float s = 0.f, sq = 0.f;
#pragma unroll
    for (int j = 0; j < 6; ++j) {
      s += v[j].x + v[j].y + v[j].z + v[j].w;
      sq += v[j].x * v[j].x + v[j].y * v[j].y + v[j].z * v[j].z + v[j].w * v[j].w;
    }
    s += __shfl_xor(s, 1);  s += __shfl_xor(s, 2);
    sq += __shfl_xor(sq, 1); sq += __shfl_xor(sq, 2);
    const float mean = s * (1.f / 96.f);
    const float var = sq * (1.f / 96.f) - mean * mean;
    const float rs = rsqrtf(var + 1e-5f);
    const float4* g4 = (const float4*)(n1w + part * 24);
    const float4* b4 = (const float4*)(n1b + part * 24);
#pragma unroll
    for (int j = 0; j < 6; ++j) {
      float4 g = g4[j], b = b4[j];
      ush4 o;
      o.x = f2bf((v[j].x - mean) * rs * g.x + b.x);
      o.y = f2bf((v[j].y - mean) * rs * g.y + b.y);
      o.z = f2bf((v[j].z - mean) * rs * g.z + b.z);
      o.w = f2bf((v[j].w - mean) * rs * g.w + b.w);
      *(ush4*)&Xo[n * XPAD + part * 24 + j * 4] = o;
    }
  }
  // no barrier: phase 1 reads only own-wave Xo rows

  // Phase 1: QKV GEMM. wave owns row-tile mt=wave; loops 18 col-tiles.
  {
    short8 a[3];
#pragma unroll
    for (int ks = 0; ks < 3; ++ks)
      a[ks] = *(const short8*)&Xo[(wave * 16 + ln) * XPAD + ks * 32 + kg * 8];
    for (int nt = 0; nt < 18; ++nt) {
      const int oc = nt * 16 + ln;
      f32x4 acc = {0.f, 0.f, 0.f, 0.f};
#pragma unroll
      for (int ks = 0; ks < 3; ++ks) {
        short8 b = *(const short8*)&wq[(size_t)oc * 96 + ks * 32 + kg * 8];
        acc = __builtin_amdgcn_mfma_f32_16x16x32_bf16(a[ks], b, acc, 0, 0, 0);
      }
      const float bias = qkvb[oc];
      if (nt < 12) {
#pragma unroll
        for (int r = 0; r < 4; ++r)
          QK[(wave * 16 + kg * 4 + r) * QKPAD + oc] = f2bf(acc[r] + bias);
      } else {
        const int vc = oc - 192, hh = vc >> 5, d = vc & 31;
        ush4 o;
        o.x = f2bf(acc[0] + bias); o.y = f2bf(acc[1] + bias);
        o.z = f2bf(acc[2] + bias); o.w = f2bf(acc[3] + bias);
        *(ush4*)&Vt[(hh * 32 + d) * VTPAD + wave * 16 + kg * 4] = o;
      }
    }
  }
  __syncthreads();  // REQUIRED: K cols, Vt, relb are read cross-wave in phase 2

  // Phase 2: per-head QK^T -> softmax (in-register) -> PV -> O (in Xo)
  const bool bz = (wz == 15), bhm = (wh == 15), bwm = (ww == 15);
  const int rowbase = wave * 16 + kg * 4;
  for (int h = 0; h < 3; ++h) {
    short8 qa = *(const short8*)&QK[(wave * 16 + ln) * QKPAD + h * 32 + kg * 8];
    f32x4 sacc[4];
#pragma unroll
    for (int nt = 0; nt < 4; ++nt) {
      short8 kb = *(const short8*)&QK[(nt * 16 + ln) * QKPAD + 96 + h * 32 + kg * 8];
      f32x4 z = {0.f, 0.f, 0.f, 0.f};
      sacc[nt] = __builtin_amdgcn_mfma_f32_16x16x32_bf16(qa, kb, z, 0, 0, 0);
    }
#pragma unroll
    for (int r = 0; r < 4; ++r) {
      const int row = rowbase + r;
      const int iz = row >> 4, ih = (row >> 2) & 3, iw = row & 3;
      const int ci = (bz ? (iz < 2 ? 9 : 18) : 0) + (bhm ? (ih < 2 ? 3 : 6) : 0) +
                     (bwm ? (iw < 2 ? 1 : 2) : 0);
      float t[4];
      float mx = -1e30f;
#pragma unroll
      for (int nt = 0; nt < 4; ++nt) {
        const int col = nt * 16 + ln;
        const int jz = col >> 4, jh = (col >> 2) & 3, jw = col & 3;
        const int cj = (bz ? (jz < 2 ? 9 : 18) : 0) + (bhm ? (jh < 2 ? 3 : 6) : 0) +
                       (bwm ? (jw < 2 ? 1 : 2) : 0);
        const int idx = (iz - jz + 3) * 49 + (ih - jh + 3) * 7 + (iw - jw + 3);
        float tv = sacc[nt][r] * SCL + relb[idx * 3 + h];
        if (ci != cj) tv -= 100.f;
        t[nt] = tv;
        mx = fmaxf(mx, tv);
      }
      mx = fmaxf(mx, __shfl_xor(mx, 1));
      mx = fmaxf(mx, __shfl_xor(mx, 2));
      mx = fmaxf(mx, __shfl_xor(mx, 4));
      mx = fmaxf(mx, __shfl_xor(mx, 8));
      float sum = 0.f;
#pragma unroll
      for (int nt = 0; nt < 4; ++nt) { t[nt] = __expf(t[nt] - mx); sum += t[nt]; }
      sum += __shfl_xor(sum, 1);
      sum += __shfl_xor(sum, 2);
      sum += __shfl_xor(sum, 4);
      sum += __shfl_xor(sum, 8);
      const float inv = 1.f / sum;
#pragma unroll
      for (int nt = 0; nt < 4; ++nt)
        Pb[row * PPAD + nt * 16 + ln] = f2bf(t[nt] * inv);
    }
    // no barrier: Pb rows are wave-local (writes+reads both in [16*wave, 16*wave+16))
#pragma unroll
    for (int dt = 0; dt < 2; ++dt) {
      f32x4 oacc = {0.f, 0.f, 0.f, 0.f};
#pragma unroll
      for (int ks = 0; ks < 2; ++ks) {
        short8 pa = *(const short8*)&Pb[(wave * 16 + ln) * PPAD + ks * 32 + kg * 8];
        short8 vb = *(const short8*)&Vt[(h * 32 + dt * 16 + ln) * VTPAD + ks * 32 + kg * 8];
        oacc = __builtin_amdgcn_mfma_f32_16x16x32_bf16(pa, vb, oacc, 0, 0, 0);
      }
#pragma unroll
      for (int r = 0; r < 4; ++r)
        Xo[(rowbase + r) * XPAD + h * 32 + dt * 16 + ln] = f2bf(oacc[r]);
    }
  }
  // no barrier: phase 3 reads only own-wave Xo rows

  // Phase 3: proj + shortcut, scatter back (reverse shift) to d_out (= x2)
  {
    short8 a[3];
#pragma unroll
    for (int ks = 0; ks < 3; ++ks)
      a[ks] = *(const short8*)&Xo[(wave * 16 + ln) * XPAD + ks * 32 + kg * 8];
    for (int nt = 0; nt < 6; ++nt) {
      f32x4 acc = {0.f, 0.f, 0.f, 0.f};
#pragma unroll
      for (int ks = 0; ks < 3; ++ks) {
        short8 b = *(const short8*)&wp[(size_t)(nt * 16 + ln) * 96 + ks * 32 + kg * 8];
        acc = __builtin_amdgcn_mfma_f32_16x16x32_bf16(a[ks], b, acc, 0, 0, 0);
      }
      const int col = nt * 16 + ln;
      const float pbv = projb[col];
#pragma unroll
      for (int r = 0; r < 4; ++r) {
        const int n = rowbase + r;
        const int lz = n >> 4, lh = (n >> 2) & 3, lw = n & 3;
        const int oz = (wz * 4 + lz + 2) & 63;
        const int oh = (wh * 4 + lh + 2) & 63;
        const int ow = (ww * 4 + lw + 2) & 63;
        const size_t tix = (size_t)((oz * 64 + oh) * 64 + ow) * 96 + col;
        out[tix] = x[tix] + acc[r] + pbv;
      }
    }
  }
}

// ---------------- fused LN2 + FC1 + GELU + FC2 + residual -------------------
// 128 rows/block, 2 row-tiles/wave, hidden dim chunked 4x96.
// ALL LDS rows are wave-local -> zero barriers; single unioned buffer Xl/H1.
__global__ __launch_bounds__(256, 4) void mlp_kernel(
    const float* __restrict__ n2w, const float* __restrict__ n2b,
    const unsigned short* __restrict__ w1, const float* __restrict__ b1,
    const unsigned short* __restrict__ w2, const float* __restrict__ b2,
    float* __restrict__ out) {
  __shared__ unsigned short Buf[128 * MXP];  // Xl, then H1 chunk (both wave-local)
  const int tid = threadIdx.x;
  const size_t r0 = (size_t)blockIdx.x * 128;
  const int wave = tid >> 6, lane = tid & 63;
  const int ln = lane & 15, kg = lane >> 4;

  // LN2 on x2 (= current d_out). rows 2 per thread-pair; wave w owns rows [32w,32w+32)
  {
    const int n = tid >> 1, part = tid & 1;
    const float* px = out + (r0 + n) * 96 + part * 48;
    float4 v[12];
#pragma unroll
    for (int j = 0; j < 12; ++j) v[j] = ((const float4*)px)[j];
    float s = 0.f, sq = 0.f;
#pragma unroll
    for (int j = 0; j < 12; ++j) {
      s += v[j].x + v[j].y + v[j].z + v[j].w;
      sq += v[j].x * v[j].x + v[j].y * v[j].y + v[j].z * v[j].z + v[j].w * v[j].w;
    }
    s += __shfl_xor(s, 1);
    sq += __shfl_xor(sq, 1);
    const float mean = s * (1.f / 96.f);
    const float var = sq * (1.f / 96.f) - mean * mean;
    const float rs = rsqrtf(var + 1e-5f);
    const float4* g4 = (const float4*)(n2w + part * 48);
    const float4* b4 = (const float4*)(n2b + part * 48);
#pragma unroll
    for (int j = 0; j < 12; ++j) {
      float4 g = g4[j], b = b4[j];
      ush4 o;
      o.x = f2bf((v[j].x - mean) * rs * g.x + b.x);
      o.y = f2bf((v[j].y - mean) * rs * g.y + b.y);
      o.z = f2bf((v[j].z - mean) * rs * g.z + b.z);
      o.w = f2bf((v[j].w - mean) * rs * g.w + b.w);
      *(ush4*)&Buf[n * MXP + part * 48 + j * 4] = o;
    }
  }
  // no barrier: wave-local

  // x_ln A-fragments into registers (Buf will be reused as H1)
  short8 a[2][3];
#pragma unroll
  for (int rt = 0; rt < 2; ++rt)
#pragma unroll
    for (int ks = 0; ks < 3; ++ks)
      a[rt][ks] = *(const short8*)&Buf[(wave * 32 + rt * 16 + ln) * MXP + ks * 32 + kg * 8];

  f32x4 facc[2][6];
#pragma unroll
  for (int rt = 0; rt < 2; ++rt)
#pragma unroll
    for (int nt = 0; nt < 6; ++nt) facc[rt][nt] = (f32x4){0.f, 0.f, 0.f, 0.f};

#pragma unroll 1
  for (int c = 0; c < 4; ++c) {
    // FC1 chunk: H1[:, c*96 .. c*96+95] -> Buf (gelu'd, bf16)
#pragma unroll
    for (int nt = 0; nt < 6; ++nt) {
      const int col = c * 96 + nt * 16 + ln;
      const float bb = b1[col];
#pragma unroll
      for (int rt = 0; rt < 2; ++rt) {
        f32x4 acc = {0.f, 0.f, 0.f, 0.f};
#pragma unroll
        for (int ks = 0; ks < 3; ++ks) {
          short8 b = *(const short8*)&w1[(size_t)col * 96 + ks * 32 + kg * 8];
          acc = __builtin_amdgcn_mfma_f32_16x16x32_bf16(a[rt][ks], b, acc, 0, 0, 0);
        }
#pragma unroll
        for (int r = 0; r < 4; ++r) {
          const float v = acc[r] + bb;
          const float gl = 0.5f * v * (1.f + erff(v * 0.70710678118654752f));
          Buf[(wave * 32 + rt * 16 + kg * 4 + r) * MXP + nt * 16 + ln] = f2bf(gl);
        }
      }
    }
    // no barrier: H1 rows wave-local
    // FC2 partial accumulate over this chunk's 96 k-values
#pragma unroll
    for (int ks = 0; ks < 3; ++ks) {
#pragma unroll
      for (int rt = 0; rt < 2; ++rt) {
        short8 pa = *(const short8*)&Buf[(wave * 32 + rt * 16 + ln) * MXP + ks * 32 + kg * 8];
#pragma unroll
        for (int nt = 0; nt < 6; ++nt) {
          short8 wb = *(const short8*)&w2[(size_t)(nt * 16 + ln) * 384 + c * 96 + ks * 32 + kg * 8];
          facc[rt][nt] = __builtin_amdgcn_mfma_f32_16x16x32_bf16(pa, wb, facc[rt][nt], 0, 0, 0);
        }
      }
    }
    // no barrier: next chunk's H1 writes are to own-wave rows
  }

  // FC2 epilogue + residual (read-modify-write d_out)
#pragma unroll
  for (int nt = 0; nt < 6; ++nt) {
    const int col = nt * 16 + ln;
    const float bb = b2[col];
#pragma unroll
    for (int rt = 0; rt < 2; ++rt) {
#pragma unroll
      for (int r = 0; r < 4; ++r) {
        const size_t row = r0 + wave * 32 + rt * 16 + kg * 4 + r;
        out[row * 96 + col] = out[row * 96 + col] + facc[rt][nt][r] + bb;
      }
    }
  }
}

extern "C" void kernel_launch(void* const* d_in, const int* in_sizes, int n_in,
                              void* d_out, int out_size, void* d_ws, size_t ws_size,
                              hipStream_t stream) {
  const float* x    = (const float*)d_in[0];
  const float* n1w  = (const float*)d_in[1];
  const float* n1b  = (const float*)d_in[2];
  const float* qkvw = (const float*)d_in[3];
  const float* qkvb = (const float*)d_in[4];
  const float* relb = (const float*)d_in[5];
  const float* pw   = (const float*)d_in[6];
  const float* pb   = (const float*)d_in[7];
  const float* n2w  = (const float*)d_in[8];
  const float* n2b  = (const float*)d_in[9];
  const float* w1   = (const float*)d_in[10];
  const float* b1   = (const float*)d_in[11];
  const float* w2   = (const float*)d_in[12];
  const float* b2   = (const float*)d_in[13];
  float* out = (float*)d_out;

  unsigned short* wsq = (unsigned short*)d_ws;   // 27648 bf16
  unsigned short* wsp = wsq + 27648;             // 9216
  unsigned short* ws1 = wsp + 9216;              // 36864
  unsigned short* ws2 = ws1 + 36864;             // 36864

  hipLaunchKernelGGL(prep_weights, dim3(144), dim3(256), 0, stream, qkvw, pw, w1, w2, wsq);
  hipLaunchKernelGGL(attn_kernel, dim3(4096), dim3(256), 0, stream,
                     x, n1w, n1b, qkvb, relb, pb, wsq, wsp, out);
  hipLaunchKernelGGL(mlp_kernel, dim3(2048), dim3(256), 0, stream,
                     n2w, n2b, ws1, b1, ws2, b2, out);
}